// Round 3
// baseline (5313.733 us; speedup 1.0000x reference)
//
#include <hip/hip_runtime.h>
#include <hip/hip_bf16.h>

#define DD 2048
#define SCALE 0.04419417382415922f   // 1/sqrt(512)

// ---------------- reduction helpers (256-thread blocks = 4 waves) ----------------

__device__ __forceinline__ float waveReduceSum(float v) {
  #pragma unroll
  for (int off = 32; off; off >>= 1) v += __shfl_down(v, off);
  return v;
}

__device__ __forceinline__ float blockReduceSum(float v, float* sred) {
  v = waveReduceSum(v);
  int wid = threadIdx.x >> 6, lane = threadIdx.x & 63;
  if (lane == 0) sred[wid] = v;
  __syncthreads();
  float r = (sred[0] + sred[1]) + (sred[2] + sred[3]);
  __syncthreads();
  return r;
}

// fused (sum, sumsq) block reduction; sred must have 8 floats.
// no trailing sync: caller syncs before sred is reused.
__device__ __forceinline__ float2 blockReduce2(float s, float ss, float* sred) {
  #pragma unroll
  for (int off = 32; off; off >>= 1) { s += __shfl_down(s, off); ss += __shfl_down(ss, off); }
  int wid = threadIdx.x >> 6, lane = threadIdx.x & 63;
  if (lane == 0) { sred[wid] = s; sred[4 + wid] = ss; }
  __syncthreads();
  float2 r;
  r.x = (sred[0] + sred[1]) + (sred[2] + sred[3]);
  r.y = (sred[4] + sred[5]) + (sred[6] + sred[7]);
  return r;
}

__device__ __forceinline__ float geluf(float x) {
  return 0.5f * x * (1.0f + erff(x * 0.7071067811865476f));
}

// ---------------- utility ----------------

__global__ void k_zero(float* p, int n) {
  int i = blockIdx.x * 256 + threadIdx.x;
  if (i < n) p[i] = 0.0f;
}

// ---------------- generic single-vector GEMV (used once for q-projection) -------

template<int NADD, bool LN, bool GELU, bool RES>
__launch_bounds__(256)
__global__ void gemv1(const float* __restrict__ W, const float* __restrict__ bias,
                      const float* __restrict__ v0, const float* __restrict__ v1,
                      const float* __restrict__ v2,
                      const float* __restrict__ g, const float* __restrict__ bln,
                      float* __restrict__ y, float* __restrict__ xside)
{
  __shared__ __align__(16) float sx[DD];
  __shared__ float sred[8];
  int tid = threadIdx.x;
  float xv[8];
  #pragma unroll
  for (int i = 0; i < 8; ++i) {
    int idx = tid + i * 256;
    float v = v0[idx];
    if (NADD >= 1) v += v1[idx];
    if (NADD >= 2) v += v2[idx];
    xv[i] = v;
  }
  if (xside != nullptr && blockIdx.x == 0) {
    #pragma unroll
    for (int i = 0; i < 8; ++i) xside[tid + i * 256] = xv[i];
  }
  if (LN) {
    float s = 0.0f;
    #pragma unroll
    for (int i = 0; i < 8; ++i) s += xv[i];
    float mean = blockReduceSum(s, sred) * (1.0f / DD);
    float vs = 0.0f;
    #pragma unroll
    for (int i = 0; i < 8; ++i) { float d = xv[i] - mean; vs += d * d; }
    float var = blockReduceSum(vs, sred) * (1.0f / DD);
    float rs = 1.0f / sqrtf(var + 1e-5f);
    #pragma unroll
    for (int i = 0; i < 8; ++i) {
      int idx = tid + i * 256;
      sx[idx] = (xv[i] - mean) * rs * g[idx] + bln[idx];
    }
  } else {
    #pragma unroll
    for (int i = 0; i < 8; ++i) sx[tid + i * 256] = xv[i];
  }
  __syncthreads();

  int wid = tid >> 6, lane = tid & 63;
  int row = blockIdx.x * 4 + wid;
  const float4* Wr = (const float4*)(W + (size_t)row * DD);
  const float4* sx4 = (const float4*)sx;
  float acc = 0.0f;
  #pragma unroll
  for (int i = 0; i < 8; ++i) {
    float4 w4 = Wr[lane + i * 64];
    float4 x4 = sx4[lane + i * 64];
    acc += w4.x * x4.x + w4.y * x4.y + w4.z * x4.z + w4.w * x4.w;
  }
  acc = waveReduceSum(acc);
  if (lane == 0) {
    float val = acc + bias[row];
    if (GELU) val = geluf(val);
    if (RES) y[row] += val; else y[row] = val;
  }
}

// ---------------- phase 1 kernels (verified correct in round 1) --------

__global__ void k_ufold(const float* __restrict__ Wfull, const float* __restrict__ qv,
                        float* __restrict__ u)
{
  int seg = blockIdx.x & 15, chunk = blockIdx.x >> 4;
  int h = seg >> 2;
  int tid = threadIdx.x;
  __shared__ float sq[128];
  if (tid < 128) sq[tid] = qv[seg * 128 + tid];
  __syncthreads();
  int d = chunk * 256 + tid;
  const float* Wp = Wfull + (size_t)(2048 + seg * 128) * DD + d;
  float acc = 0.0f;
  #pragma unroll 4
  for (int j = 0; j < 128; ++j) acc += Wp[(size_t)j * DD] * sq[j];
  atomicAdd(&u[(h << 11) + d], acc * SCALE);
}

__global__ void k_cfold(const float* __restrict__ qv, const float* __restrict__ inb,
                        float* __restrict__ c)
{
  __shared__ float sred[8];
  int tid = threadIdx.x;
  for (int h = 0; h < 4; ++h) {
    float s = 0.0f;
    for (int j = tid; j < 512; j += 256) s += qv[h * 512 + j] * inb[2048 + h * 512 + j];
    float tot = blockReduceSum(s, sred);
    if (tid == 0) c[h] = tot * SCALE;
    __syncthreads();
  }
}

__global__ void k_scores(const float* __restrict__ x, const float* __restrict__ u,
                         const float* __restrict__ c, float* __restrict__ sc)
{
  int blk = blockIdx.x;
  int b = blk >> 10, t = blk & 1023;
  int tid = threadIdx.x, wid = tid >> 6, lane = tid & 63;
  const float4* xr = (const float4*)(x + (size_t)blk * DD);
  float acc[4] = {0, 0, 0, 0};
  #pragma unroll
  for (int i = 0; i < 2; ++i) {
    int f = tid + i * 256;
    float4 x4 = xr[f];
    #pragma unroll
    for (int h = 0; h < 4; ++h) {
      float4 u4 = ((const float4*)(u + (h << 11)))[f];
      acc[h] += x4.x * u4.x + x4.y * u4.y + x4.z * u4.z + x4.w * u4.w;
    }
  }
  __shared__ float sred[4][4];
  #pragma unroll
  for (int h = 0; h < 4; ++h) {
    float v = waveReduceSum(acc[h]);
    if (lane == 0) sred[h][wid] = v;
  }
  __syncthreads();
  if (tid < 4) {
    float v = sred[tid][0] + sred[tid][1] + sred[tid][2] + sred[tid][3] + c[tid];
    sc[((size_t)(b * 4 + tid) << 10) + t] = v;
  }
}

__global__ void k_softmax(float* __restrict__ s)
{
  __shared__ float sred[8];
  int tid = threadIdx.x, wid = tid >> 6, lane = tid & 63;
  float* p = s + ((size_t)blockIdx.x << 10);
  float v[4];
  #pragma unroll
  for (int i = 0; i < 4; ++i) v[i] = p[tid + i * 256];
  float m = fmaxf(fmaxf(v[0], v[1]), fmaxf(v[2], v[3]));
  #pragma unroll
  for (int off = 32; off; off >>= 1) m = fmaxf(m, __shfl_down(m, off));
  if (lane == 0) sred[wid] = m;
  __syncthreads();
  m = fmaxf(fmaxf(sred[0], sred[1]), fmaxf(sred[2], sred[3]));
  __syncthreads();
  float e[4], sum = 0.0f;
  #pragma unroll
  for (int i = 0; i < 4; ++i) { e[i] = expf(v[i] - m); sum += e[i]; }
  float tot = blockReduceSum(sum, sred);
  float inv = 1.0f / tot;
  #pragma unroll
  for (int i = 0; i < 4; ++i) p[tid + i * 256] = e[i] * inv;
}

__global__ void k_xbar_part(const float* __restrict__ x, const float* __restrict__ att,
                            float* __restrict__ part)
{
  int blk = blockIdx.x;
  int seg = blk & 7, chunk = (blk >> 3) & 7, b = blk >> 6;
  int tid = threadIdx.x;
  __shared__ float satt[4][128];
  for (int i = tid; i < 512; i += 256) {
    int h = i >> 7, j = i & 127;
    satt[h][j] = att[((size_t)(b * 4 + h) << 10) + seg * 128 + j];
  }
  __syncthreads();
  int d = chunk * 256 + tid;
  const float* xb = x + ((size_t)b * 1024 + seg * 128) * DD + d;
  float a0 = 0, a1 = 0, a2 = 0, a3 = 0;
  #pragma unroll 4
  for (int j = 0; j < 128; ++j) {
    float xv = xb[(size_t)j * DD];
    a0 += satt[0][j] * xv; a1 += satt[1][j] * xv;
    a2 += satt[2][j] * xv; a3 += satt[3][j] * xv;
  }
  size_t base = ((size_t)(b * 8 + seg) * 4);
  part[((base + 0) << 11) + d] = a0;
  part[((base + 1) << 11) + d] = a1;
  part[((base + 2) << 11) + d] = a2;
  part[((base + 3) << 11) + d] = a3;
}

__global__ void k_xbar_red(const float* __restrict__ part, float* __restrict__ xbar)
{
  int i = blockIdx.x * 256 + threadIdx.x;
  int d = i & 2047; int h = (i >> 11) & 3; int b = i >> 13;
  float s = 0.0f;
  #pragma unroll
  for (int seg = 0; seg < 8; ++seg)
    s += part[(((size_t)(b * 8 + seg) * 4 + h) << 11) + d];
  xbar[i] = s;
}

__launch_bounds__(256)
__global__ void k_vproj(const float* __restrict__ inW, const float* __restrict__ inB,
                        const float* __restrict__ xbar, float* __restrict__ o)
{
  __shared__ __align__(16) float sv[8][DD];
  int tid = threadIdx.x, wid = tid >> 6, lane = tid & 63;
  int row0 = blockIdx.x * 8;
  int h = row0 >> 9;
  int rowA = row0 + wid, rowB = row0 + 4 + wid;
  const float4* WA = (const float4*)(inW + (size_t)(4096 + rowA) * DD);
  const float4* WB = (const float4*)(inW + (size_t)(4096 + rowB) * DD);
  float4 wa[8], wb[8];
  #pragma unroll
  for (int i = 0; i < 8; ++i) { wa[i] = WA[lane + i * 64]; wb[i] = WB[lane + i * 64]; }
  float accA[16], accB[16];
  #pragma unroll
  for (int b = 0; b < 16; ++b) { accA[b] = 0; accB[b] = 0; }
  for (int half = 0; half < 2; ++half) {
    __syncthreads();
    for (int i = tid; i < 8 * 512; i += 256) {
      int b = i >> 9, f = i & 511;
      ((float4*)&sv[b][0])[f] =
          ((const float4*)(xbar + (((size_t)(half * 8 + b) * 4 + h) << 11)))[f];
    }
    __syncthreads();
    #pragma unroll
    for (int i = 0; i < 8; ++i) {
      int f = lane + i * 64;
      #pragma unroll
      for (int b = 0; b < 8; ++b) {
        float4 x4 = ((const float4*)&sv[b][0])[f];
        accA[half * 8 + b] += wa[i].x * x4.x + wa[i].y * x4.y + wa[i].z * x4.z + wa[i].w * x4.w;
        accB[half * 8 + b] += wb[i].x * x4.x + wb[i].y * x4.y + wb[i].z * x4.z + wb[i].w * x4.w;
      }
    }
  }
  #pragma unroll
  for (int b = 0; b < 16; ++b) {
    float v = waveReduceSum(accA[b]);
    if (lane == 0) o[((size_t)b << 11) + rowA] = v + inB[4096 + rowA];
    v = waveReduceSum(accB[b]);
    if (lane == 0) o[((size_t)b << 11) + rowB] = v + inB[4096 + rowB];
  }
}

template<bool GELU>
__launch_bounds__(256)
__global__ void gemvB(const float* __restrict__ W, const float* __restrict__ bias,
                      const float* __restrict__ vin, float* __restrict__ y)
{
  __shared__ __align__(16) float sv[8][DD];
  int tid = threadIdx.x, wid = tid >> 6, lane = tid & 63;
  int row0 = blockIdx.x * 8;
  int rowA = row0 + wid, rowB = row0 + 4 + wid;
  const float4* WA = (const float4*)(W + (size_t)rowA * DD);
  const float4* WB = (const float4*)(W + (size_t)rowB * DD);
  float4 wa[8], wb[8];
  #pragma unroll
  for (int i = 0; i < 8; ++i) { wa[i] = WA[lane + i * 64]; wb[i] = WB[lane + i * 64]; }
  float accA[16], accB[16];
  #pragma unroll
  for (int b = 0; b < 16; ++b) { accA[b] = 0; accB[b] = 0; }
  for (int half = 0; half < 2; ++half) {
    __syncthreads();
    for (int i = tid; i < 8 * 512; i += 256) {
      int b = i >> 9, f = i & 511;
      ((float4*)&sv[b][0])[f] =
          ((const float4*)(vin + ((size_t)(half * 8 + b) << 11)))[f];
    }
    __syncthreads();
    #pragma unroll
    for (int i = 0; i < 8; ++i) {
      int f = lane + i * 64;
      #pragma unroll
      for (int b = 0; b < 8; ++b) {
        float4 x4 = ((const float4*)&sv[b][0])[f];
        accA[half * 8 + b] += wa[i].x * x4.x + wa[i].y * x4.y + wa[i].z * x4.z + wa[i].w * x4.w;
        accB[half * 8 + b] += wb[i].x * x4.x + wb[i].y * x4.y + wb[i].z * x4.z + wb[i].w * x4.w;
      }
    }
  }
  #pragma unroll
  for (int b = 0; b < 16; ++b) {
    float v = waveReduceSum(accA[b]);
    if (lane == 0) {
      float r = v + bias[rowA];
      if (GELU) r = geluf(r);
      y[((size_t)b << 11) + rowA] = r;
    }
    v = waveReduceSum(accB[b]);
    if (lane == 0) {
      float r = v + bias[rowB];
      if (GELU) r = geluf(r);
      y[((size_t)b << 11) + rowB] = r;
    }
  }
}

// ================= persistent scan kernel =================
// 512 blocks x 256 threads, 2 blocks/CU guaranteed by __launch_bounds__(256,2)
// (LDS 8.3KB/block, low VGPR). 256 GEMV stages separated by a two-level
// monotonic grid barrier (8 group counters -> 1 root counter).

struct ScanArgs {
  const float *Lwv, *Lbv, *Low, *Lob, *Lf1, *Lf1b, *Lf2, *Lf2b;
  const float *Ln1g, *Ln1b, *Ln2g, *Ln2b;
  const float *Hwv, *Hbv, *How, *Hob, *Hf1, *Hf1b, *Hf2, *Hf2b;
  const float *Hn1g, *Hn1b, *Hn2g, *Hn2b;
  const float *abuf;
  float *zL0, *zL1, *zH0, *zH1, *tbuf, *hbuf;
  const float *norm_g, *norm_b;
  float *out;
  unsigned *root, *grp;   // grp[g*32], g<8
};

__device__ __forceinline__ void gridBar(unsigned* root, unsigned* grp, int epoch) {
  __syncthreads();
  if (threadIdx.x == 0) {
    unsigned g = (unsigned)blockIdx.x >> 6;
    unsigned old = __hip_atomic_fetch_add(&grp[g * 32], 1u,
                                          __ATOMIC_ACQ_REL, __HIP_MEMORY_SCOPE_AGENT);
    if (old == 64u * (unsigned)epoch - 1u)   // last arrival of this group
      __hip_atomic_fetch_add(root, 1u, __ATOMIC_RELEASE, __HIP_MEMORY_SCOPE_AGENT);
    unsigned target = 8u * (unsigned)epoch;
    while (__hip_atomic_load(root, __ATOMIC_RELAXED, __HIP_MEMORY_SCOPE_AGENT) < target) {
      __builtin_amdgcn_s_sleep(1);   // cut spin contention on the root line
    }
    __builtin_amdgcn_fence(__ATOMIC_ACQUIRE, "agent");
  }
  __syncthreads();
}

// one GEMV stage: y[row] (=|+=) act( W[row,:] . maybeLN(v0+v1+v2) + bias[row] )
// weights prefetched into registers BEFORE the LN chain to hide load latency.
template<int NADD, bool LN, bool GELU, bool RES, bool XSIDE>
__device__ __forceinline__ void stage(
    const float* __restrict__ W, const float* __restrict__ bias,
    const float* __restrict__ v0, const float* __restrict__ v1,
    const float* __restrict__ v2,
    const float* __restrict__ g, const float* __restrict__ bln,
    float* __restrict__ y, float* __restrict__ xside,
    float* sx, float* sred)
{
  int tid = threadIdx.x, wid = tid >> 6, lane = tid & 63;
  int row = blockIdx.x * 4 + wid;
  const float4* Wr = (const float4*)(W + (size_t)row * DD);
  float4 wa[8];
  #pragma unroll
  for (int i = 0; i < 8; ++i) wa[i] = Wr[lane + i * 64];   // in flight during LN

  float4 xv[2];
  #pragma unroll
  for (int i = 0; i < 2; ++i) {
    int idx = tid + i * 256;
    float4 a = ((const float4*)v0)[idx];
    if (NADD >= 1) { float4 b = ((const float4*)v1)[idx];
                     a.x += b.x; a.y += b.y; a.z += b.z; a.w += b.w; }
    if (NADD >= 2) { float4 b = ((const float4*)v2)[idx];
                     a.x += b.x; a.y += b.y; a.z += b.z; a.w += b.w; }
    xv[i] = a;
  }
  if (XSIDE && blockIdx.x == 0) {
    #pragma unroll
    for (int i = 0; i < 2; ++i) ((float4*)xside)[tid + i * 256] = xv[i];
  }
  if (LN) {
    float s = 0.0f, ss = 0.0f;
    #pragma unroll
    for (int i = 0; i < 2; ++i) {
      s  += xv[i].x + xv[i].y + xv[i].z + xv[i].w;
      ss += xv[i].x * xv[i].x + xv[i].y * xv[i].y + xv[i].z * xv[i].z + xv[i].w * xv[i].w;
    }
    float2 r = blockReduce2(s, ss, sred);
    float mean = r.x * (1.0f / DD);
    float var = r.y * (1.0f / DD) - mean * mean;
    float rs = 1.0f / sqrtf(var + 1e-5f);
    #pragma unroll
    for (int i = 0; i < 2; ++i) {
      int idx = tid + i * 256;
      float4 g4 = ((const float4*)g)[idx];
      float4 b4 = ((const float4*)bln)[idx];
      float4 t;
      t.x = (xv[i].x - mean) * rs * g4.x + b4.x;
      t.y = (xv[i].y - mean) * rs * g4.y + b4.y;
      t.z = (xv[i].z - mean) * rs * g4.z + b4.z;
      t.w = (xv[i].w - mean) * rs * g4.w + b4.w;
      ((float4*)sx)[idx] = t;
    }
  } else {
    #pragma unroll
    for (int i = 0; i < 2; ++i) ((float4*)sx)[tid + i * 256] = xv[i];
  }
  __syncthreads();
  const float4* sx4 = (const float4*)sx;
  float acc = 0.0f;
  #pragma unroll
  for (int i = 0; i < 8; ++i) {
    float4 x4 = sx4[lane + i * 64];
    acc += wa[i].x * x4.x + wa[i].y * x4.y + wa[i].z * x4.z + wa[i].w * x4.w;
  }
  acc = waveReduceSum(acc);
  if (lane == 0) {
    float val = acc + bias[row];
    if (GELU) val = geluf(val);
    if (RES) y[row] += val; else y[row] = val;
  }
}

__global__ __launch_bounds__(256, 2) void k_scan(ScanArgs a)
{
  __shared__ __align__(16) float sx[DD];
  __shared__ float sred[8];
  float* zL[2] = { a.zL0, a.zL1 };
  float* zH[2] = { a.zH0, a.zH1 };
  int li = 0, hi = 0;
  int epoch = 0;
  #define BAR() gridBar(a.root, a.grp, ++epoch)

  for (int s = 0; s < 16; ++s) {
    const float* xt = a.abuf + (size_t)s * DD;
    for (int r = 0; r < 3; ++r) {
      stage<2, true, false, false, true >(a.Lwv, a.Lbv, zL[li], zH[hi], xt,
                                          a.Ln1g, a.Ln1b, a.tbuf, zL[li ^ 1], sx, sred); BAR();
      stage<0, false, false, true, false>(a.Low, a.Lob, a.tbuf, nullptr, nullptr,
                                          nullptr, nullptr, zL[li ^ 1], nullptr, sx, sred); BAR();
      stage<0, true, true, false, false>(a.Lf1, a.Lf1b, zL[li ^ 1], nullptr, nullptr,
                                          a.Ln2g, a.Ln2b, a.hbuf, nullptr, sx, sred); BAR();
      stage<0, false, false, true, false>(a.Lf2, a.Lf2b, a.hbuf, nullptr, nullptr,
                                          nullptr, nullptr, zL[li ^ 1], nullptr, sx, sred); BAR();
      li ^= 1;
    }
    stage<1, true, false, false, true >(a.Hwv, a.Hbv, zH[hi], zL[li], nullptr,
                                        a.Hn1g, a.Hn1b, a.tbuf, zH[hi ^ 1], sx, sred); BAR();
    stage<0, false, false, true, false>(a.How, a.Hob, a.tbuf, nullptr, nullptr,
                                        nullptr, nullptr, zH[hi ^ 1], nullptr, sx, sred); BAR();
    stage<0, true, true, false, false>(a.Hf1, a.Hf1b, zH[hi ^ 1], nullptr, nullptr,
                                        a.Hn2g, a.Hn2b, a.hbuf, nullptr, sx, sred); BAR();
    stage<0, false, false, true, false>(a.Hf2, a.Hf2b, a.hbuf, nullptr, nullptr,
                                        nullptr, nullptr, zH[hi ^ 1], nullptr, sx, sred); BAR();
    hi ^= 1;
  }
  #undef BAR

  // final LayerNorm on zH -> out, block 0 only (last BAR made zH visible)
  if (blockIdx.x == 0) {
    int tid = threadIdx.x;
    const float* z = zH[hi];
    float xv[8];
    #pragma unroll
    for (int i = 0; i < 8; ++i) xv[i] = z[tid + i * 256];
    float s = 0.0f, ss = 0.0f;
    #pragma unroll
    for (int i = 0; i < 8; ++i) { s += xv[i]; ss += xv[i] * xv[i]; }
    float2 r = blockReduce2(s, ss, sred);
    float mean = r.x * (1.0f / DD);
    float var = r.y * (1.0f / DD) - mean * mean;
    float rs = 1.0f / sqrtf(var + 1e-5f);
    #pragma unroll
    for (int i = 0; i < 8; ++i) {
      int idx = tid + i * 256;
      a.out[idx] = (xv[i] - mean) * rs * a.norm_g[idx] + a.norm_b[idx];
    }
  }
}

// ======================= host side =======================

extern "C" void kernel_launch(void* const* d_in, const int* in_sizes, int n_in,
                              void* d_out, int out_size, void* d_ws, size_t ws_size,
                              hipStream_t stream)
{
  const float* x          = (const float*)d_in[0];
  const float* gq         = (const float*)d_in[1];
  const float* attn_in_w  = (const float*)d_in[2];
  const float* attn_in_b  = (const float*)d_in[3];
  const float* attn_out_w = (const float*)d_in[4];
  const float* attn_out_b = (const float*)d_in[5];
  const float* mlp1_w     = (const float*)d_in[6];
  const float* mlp1_b     = (const float*)d_in[7];
  const float* mlp2_w     = (const float*)d_in[8];
  const float* mlp2_b     = (const float*)d_in[9];

  float* ws = (float*)d_ws;
  // layout (floats)
  unsigned* root = (unsigned*)ws;              // ws[0]
  unsigned* grp  = (unsigned*)(ws + 16);       // ws[16..272), stride 32
  float* u     = ws + 512;      // 8192
  float* zL0   = ws + 8704;     // 2048
  float* zL1   = ws + 10752;
  float* zH0   = ws + 12800;
  float* zH1   = ws + 14848;
  float* tbuf  = ws + 16896;
  float* hbuf  = ws + 18944;
  float* qv    = ws + 20992;
  float* c     = ws + 23040;    // pad 64
  float* sc    = ws + 23104;    // 65536
  float* xbar  = ws + 88640;    // 131072
  float* o     = ws + 219712;   // 32768
  float* a0    = ws + 252480;
  float* a1    = ws + 285248;
  float* abuf  = ws + 318016;
  float* part  = ws + 350784;   // 1048576

  // zero: counters + u + zL0/zL1/zH0/zH1  (ws[0 .. 16896))
  k_zero<<<66, 256, 0, stream>>>(ws, 16896);

  // --- phase 1: a = MLP(out_proj(attn(q_global, x, x))) ---
  gemv1<0, false, false, false><<<512, 256, 0, stream>>>(
      attn_in_w, attn_in_b, gq, nullptr, nullptr, nullptr, nullptr, qv, nullptr);
  k_ufold<<<128, 256, 0, stream>>>(attn_in_w, qv, u);
  k_cfold<<<1, 256, 0, stream>>>(qv, attn_in_b, c);
  k_scores<<<16384, 256, 0, stream>>>(x, u, c, sc);
  k_softmax<<<64, 256, 0, stream>>>(sc);
  k_xbar_part<<<1024, 256, 0, stream>>>(x, sc, part);
  k_xbar_red<<<512, 256, 0, stream>>>(part, xbar);
  k_vproj<<<256, 256, 0, stream>>>(attn_in_w, attn_in_b, xbar, o);
  gemvB<false><<<256, 256, 0, stream>>>(attn_out_w, attn_out_b, o, a0);
  gemvB<true ><<<256, 256, 0, stream>>>(mlp1_w, mlp1_b, a0, a1);
  gemvB<false><<<256, 256, 0, stream>>>(mlp2_w, mlp2_b, a1, abuf);

  // --- phase 2: persistent scan kernel, 256 GEMV stages, 256 grid barriers ---
  ScanArgs sa;
  sa.Hwv = (const float*)d_in[10] + (size_t)4096 * DD;  // h_attn_in_w rows 4096..6143
  sa.Hbv = (const float*)d_in[11] + 4096;
  sa.How = (const float*)d_in[12];
  sa.Hob = (const float*)d_in[13];
  sa.Hn1g = (const float*)d_in[14]; sa.Hn1b = (const float*)d_in[15];
  sa.Hn2g = (const float*)d_in[16]; sa.Hn2b = (const float*)d_in[17];
  sa.Hf1 = (const float*)d_in[18]; sa.Hf1b = (const float*)d_in[19];
  sa.Hf2 = (const float*)d_in[20]; sa.Hf2b = (const float*)d_in[21];
  sa.Lwv = (const float*)d_in[22] + (size_t)4096 * DD;
  sa.Lbv = (const float*)d_in[23] + 4096;
  sa.Low = (const float*)d_in[24];
  sa.Lob = (const float*)d_in[25];
  sa.Ln1g = (const float*)d_in[26]; sa.Ln1b = (const float*)d_in[27];
  sa.Ln2g = (const float*)d_in[28]; sa.Ln2b = (const float*)d_in[29];
  sa.Lf1 = (const float*)d_in[30]; sa.Lf1b = (const float*)d_in[31];
  sa.Lf2 = (const float*)d_in[32]; sa.Lf2b = (const float*)d_in[33];
  sa.abuf = abuf;
  sa.zL0 = zL0; sa.zL1 = zL1; sa.zH0 = zH0; sa.zH1 = zH1;
  sa.tbuf = tbuf; sa.hbuf = hbuf;
  sa.norm_g = (const float*)d_in[34];
  sa.norm_b = (const float*)d_in[35];
  sa.out = (float*)d_out;
  sa.root = root; sa.grp = grp;

  k_scan<<<512, 256, 0, stream>>>(sa);
}